// Round 3
// baseline (10351.345 us; speedup 1.0000x reference)
//
#include <hip/hip_runtime.h>

#define NNODES 20000
#define NEDGES 640000
#define NGRAPHS 16
#define NO     256
#define NNF    58
#define KPAD   64
#define EMBD   512
#define NL     28
#define NBLK   40         // src blocks of 512 nodes (1 MB of u/v each)
#define BSHIFT 9
#define T2     (NNODES * NBLK)   // 800000 histogram entries

__device__ __forceinline__ float fast_tanh(float x) {
    float e = __expf(2.0f * x);
    return 1.0f - 2.0f / (e + 1.0f);
}

// ---------------- segmented CSR build: per-dst lists, src-block-sorted ----------------
__global__ __launch_bounds__(256) void k_hist2(const int* __restrict__ src, const int* __restrict__ dst,
                                               int* __restrict__ counts) {
    int e = blockIdx.x * 256 + threadIdx.x;
    if (e < NEDGES) atomicAdd(&counts[dst[e] * NBLK + (src[e] >> BSHIFT)], 1);
}

// exclusive scan of counts[T2] -> offs2 AND cur2 (two copies so fill can bump cur2)
__global__ __launch_bounds__(1024) void k_scan2(const int* __restrict__ counts,
                                                int* __restrict__ offs2, int* __restrict__ cur2) {
    __shared__ int part[1024];
    int t = threadIdx.x;
    const int CH = (T2 + 1023) / 1024;  // 782
    int base = t * CH;
    int s = 0;
    for (int i = 0; i < CH; ++i) { int idx = base + i; if (idx < T2) s += counts[idx]; }
    part[t] = s;
    __syncthreads();
    if (t == 0) { int acc = 0; for (int i = 0; i < 1024; ++i) { int v = part[i]; part[i] = acc; acc += v; } }
    __syncthreads();
    int acc = part[t];
    for (int i = 0; i < CH; ++i) {
        int idx = base + i;
        if (idx < T2) { offs2[idx] = acc; cur2[idx] = acc; acc += counts[idx]; }
    }
    if (t == 1023) { offs2[T2] = acc; }
}

// per-dst begin offsets for the edge kernel (end = offs[n+1])
__global__ __launch_bounds__(256) void k_offc(const int* __restrict__ offs2, int* __restrict__ offs) {
    int i = blockIdx.x * 256 + threadIdx.x;
    if (i <= NNODES) offs[i] = (i < NNODES) ? offs2[(size_t)i * NBLK] : NEDGES;
}

__global__ __launch_bounds__(256) void k_fill2(const int* __restrict__ src, const int* __restrict__ dst,
                                               const float* __restrict__ ef, int* __restrict__ cur2,
                                               int* __restrict__ srcp, float* __restrict__ efp) {
    int e = blockIdx.x * 256 + threadIdx.x;
    if (e < NEDGES) {
        int s = src[e], d = dst[e];
        int pos = atomicAdd(&cur2[d * NBLK + (s >> BSHIFT)], 1);
        srcp[pos] = s;
        efp[pos]  = ef[e];
    }
}

// ---------------- layer-0 input pad: [20000][58] -> [20000][64] ----------------
__global__ __launch_bounds__(256) void k_padx(const float* __restrict__ x, float* __restrict__ xpad) {
    int i = blockIdx.x * 256 + threadIdx.x;
    if (i < NNODES * KPAD) {
        int r = i >> 6, c = i & 63;
        xpad[i] = (c < NNF) ? x[r * NNF + c] : 0.f;
    }
}

// ---------------- weight precompute ----------------
// Wcat layout: [NL][768][NO] row-major (layer 0 uses only first NNF cols, rest zero).
// rows 0..255 = Wn; 256..511 = (Wm*diag(We))@Wn; 512..767 = (Wm*diag(be))@Wn
__global__ __launch_bounds__(256) void k_prep(
    const float* __restrict__ Wn0, const float* __restrict__ bn0,
    const float* __restrict__ We0, const float* __restrict__ be0,
    const float* __restrict__ Wm0, const float* __restrict__ bm0,
    const float* __restrict__ Wn,  const float* __restrict__ bn,
    const float* __restrict__ We,  const float* __restrict__ be,
    const float* __restrict__ Wm,  const float* __restrict__ bm,
    float* __restrict__ Wcat, float* __restrict__ bcat) {
    int l = blockIdx.x / 768;
    int r = blockIdx.x % 768;
    int k = threadIdx.x;  // 0..255
    const float *wn, *bnv, *wev, *bev, *wm, *bmv;
    int K;
    if (l == 0) { wn = Wn0; bnv = bn0; wev = We0; bev = be0; wm = Wm0; bmv = bm0; K = NNF; }
    else {
        int j = l - 1;
        wn = Wn + (size_t)j * NO * NO; bnv = bn + j * NO;
        wev = We + j * NO;             bev = be + j * NO;
        wm = Wm + (size_t)j * NO * NO; bmv = bm + j * NO;
        K = NO;
    }
    float* Wout = Wcat + ((size_t)l * 768 + r) * NO;
    float* bout = bcat + l * 768 + r;
    if (r < NO) {
        if (k < K) Wout[k] = wn[(size_t)r * K + k];
        else       Wout[k] = 0.f;
        if (k == 0) *bout = bnv[r];
        return;
    }
    int i = (r < 512) ? r - 256 : r - 512;
    const float* scale = (r < 512) ? wev : bev;
    __shared__ float coeff[NO];
    coeff[k] = wm[(size_t)i * NO + k] * scale[k];
    __syncthreads();
    float acc = 0.f;
    if (k < K) {
        for (int j = 0; j < NO; ++j) acc += coeff[j] * wn[(size_t)j * K + k];
        Wout[k] = acc;
    } else Wout[k] = 0.f;
    if (k == 0) {
        float b = 0.f;
        for (int j = 0; j < NO; ++j) b += coeff[j] * bnv[j];
        if (r >= 512) b += bmv[i];
        *bout = b;
    }
}

// ---------------- fused layer GEMM: C[M x 768] = A[M x K] @ W[768 x K].T + bias ----------------
// Output row layout (768 floats): [hn(256) | uv interleaved: u_i -> 256+8*(i>>2)+(i&3), v_i -> +4]
#define BM 128
#define BN 64
#define BK 16
__global__ __launch_bounds__(256) void k_gemm(const float* __restrict__ A, const float* __restrict__ W,
                                              const float* __restrict__ bias, float* __restrict__ C,
                                              int M, int K) {
    __shared__ float sA[BK][BM + 4];
    __shared__ float sB[BK][BN + 4];
    int bn0 = blockIdx.x * BN;
    int bm0 = blockIdx.y * BM;
    int t = threadIdx.x;
    int tx = t & 15, ty = t >> 4;
    float acc[8][4] = {};
    for (int k0 = 0; k0 < K; k0 += BK) {
        #pragma unroll
        for (int rep = 0; rep < 2; ++rep) {
            int idx = t + rep * 256;
            int r = idx >> 2, cq = (idx & 3) * 4;
            int gr = bm0 + r;
            float4 a4 = {0.f, 0.f, 0.f, 0.f};
            if (gr < M) a4 = *(const float4*)(A + (size_t)gr * K + k0 + cq);
            sA[cq + 0][r] = a4.x; sA[cq + 1][r] = a4.y; sA[cq + 2][r] = a4.z; sA[cq + 3][r] = a4.w;
        }
        {
            int r = t >> 2, cq = (t & 3) * 4;
            float4 b4 = *(const float4*)(W + (size_t)(bn0 + r) * NO + k0 + cq);
            sB[cq + 0][r] = b4.x; sB[cq + 1][r] = b4.y; sB[cq + 2][r] = b4.z; sB[cq + 3][r] = b4.w;
        }
        __syncthreads();
        #pragma unroll
        for (int kk = 0; kk < BK; ++kk) {
            float a[8], b[4];
            *(float4*)a       = *(const float4*)&sA[kk][ty * 8];
            *(float4*)(a + 4) = *(const float4*)&sA[kk][ty * 8 + 4];
            *(float4*)b       = *(const float4*)&sB[kk][tx * 4];
            #pragma unroll
            for (int i = 0; i < 8; ++i)
                #pragma unroll
                for (int j = 0; j < 4; ++j) acc[i][j] += a[i] * b[j];
        }
        __syncthreads();
    }
    int n0 = bn0 + tx * 4;
    size_t off;
    if (n0 < 256)      off = n0;
    else if (n0 < 512) off = 256 + 8 * ((size_t)(n0 - 256) >> 2);
    else               off = 260 + 8 * ((size_t)(n0 - 512) >> 2);
    float4 bi = *(const float4*)(bias + n0);
    #pragma unroll
    for (int i = 0; i < 8; ++i) {
        int gr = bm0 + ty * 8 + i;
        if (gr >= M) continue;
        float4 o = {acc[i][0] + bi.x, acc[i][1] + bi.y, acc[i][2] + bi.z, acc[i][3] + bi.w};
        *(float4*)(C + (size_t)gr * 768 + off) = o;
    }
}

// ---------------- edge aggregation: wave-per-node, shfl-broadcast edge meta ----------------
// (unchanged from r2 — the src-block-sorted lists give L2 temporal locality for free)
__global__ __launch_bounds__(256) void k_edge(const float* __restrict__ huv, const int* __restrict__ offs,
                                              const int* __restrict__ srcp, const float* __restrict__ efp,
                                              float* __restrict__ hout) {
    int wv = threadIdx.x >> 6;
    int lane = threadIdx.x & 63;
    int n = blockIdx.x * 4 + wv;
    int e0 = offs[n], e1 = offs[n + 1];
    float a0 = 0.f, a1 = 0.f, a2 = 0.f, a3 = 0.f;
    for (int eb = e0; eb < e1; eb += 64) {
        int cnt = e1 - eb; if (cnt > 64) cnt = 64;
        int sv = 0; float fv = 0.f;
        if (lane < cnt) { sv = srcp[eb + lane]; fv = efp[eb + lane]; }
        #pragma unroll 4
        for (int i = 0; i < cnt; ++i) {
            int ss = __shfl(sv, i);
            float ff = __shfl(fv, i);
            const float* p = huv + (size_t)ss * 768 + 256 + lane * 8;
            float4 u4 = *(const float4*)p;
            float4 v4 = *(const float4*)(p + 4);
            a0 += fast_tanh(ff * u4.x + v4.x);
            a1 += fast_tanh(ff * u4.y + v4.y);
            a2 += fast_tanh(ff * u4.z + v4.z);
            a3 += fast_tanh(ff * u4.w + v4.w);
        }
    }
    float4 hn4 = *(const float4*)(huv + (size_t)n * 768 + lane * 4);
    float4 o = {hn4.x + a0, hn4.y + a1, hn4.z + a2, hn4.w + a3};
    *(float4*)(hout + (size_t)n * NO + lane * 4) = o;
}

// ---------------- pooling via sorted-batch ranges ----------------
__device__ __forceinline__ int lower_bound_g(const int* __restrict__ batch, int target) {
    int lo = 0, hi = NNODES;
    while (lo < hi) { int mid = (lo + hi) >> 1; if (batch[mid] < target) lo = mid + 1; else hi = mid; }
    return lo;
}

__global__ __launch_bounds__(256) void k_pool2(const float* __restrict__ h, const int* __restrict__ batch,
                                               float* __restrict__ sums) {
    int g = blockIdx.x, chunk = blockIdx.y;
    __shared__ int sh[2];
    if (threadIdx.x < 2) sh[threadIdx.x] = lower_bound_g(batch, g + (int)threadIdx.x);
    __syncthreads();
    int lo = sh[0], hi = sh[1];
    float acc = 0.f;
    for (int r = lo + chunk; r < hi; r += 8)
        acc += h[(size_t)r * NO + threadIdx.x];
    atomicAdd(&sums[g * NO + threadIdx.x], acc);
}

__global__ __launch_bounds__(512) void k_final(const float* __restrict__ sums, const int* __restrict__ batch,
                                               const float* __restrict__ Wlin, const float* __restrict__ blin,
                                               float* __restrict__ out) {
    int g = blockIdx.x, t = threadIdx.x;
    __shared__ int sh[2];
    __shared__ float m[NO];
    if (t < 2) sh[t] = lower_bound_g(batch, g + t);
    __syncthreads();
    float inv = 1.f / (float)(sh[1] - sh[0]);
    if (t < NO) m[t] = sums[g * NO + t] * inv;
    __syncthreads();
    float acc = blin[t];
    for (int k = 0; k < NO; ++k) acc += m[k] * Wlin[(size_t)t * NO + k];
    out[(size_t)g * EMBD + t] = acc;
}

extern "C" void kernel_launch(void* const* d_in, const int* in_sizes, int n_in,
                              void* d_out, int out_size, void* d_ws, size_t ws_size,
                              hipStream_t stream) {
    const float* x     = (const float*)d_in[0];
    const int*   ei    = (const int*)d_in[1];
    const float* ef    = (const float*)d_in[2];
    const int*   batch = (const int*)d_in[3];
    const float* Wn0 = (const float*)d_in[4];
    const float* bn0 = (const float*)d_in[5];
    const float* We0 = (const float*)d_in[6];
    const float* be0 = (const float*)d_in[7];
    const float* Wm0 = (const float*)d_in[8];
    const float* bm0 = (const float*)d_in[9];
    const float* Wn  = (const float*)d_in[10];
    const float* bn  = (const float*)d_in[11];
    const float* We  = (const float*)d_in[12];
    const float* be  = (const float*)d_in[13];
    const float* Wm  = (const float*)d_in[14];
    const float* bm  = (const float*)d_in[15];
    const float* Wlin = (const float*)d_in[16];
    const float* blin = (const float*)d_in[17];
    float* out = (float*)d_out;

    // workspace carve (256B aligned slices)
    char* p = (char*)d_ws;
    auto carve = [&](size_t bytes) { char* q = p; p += (bytes + 255) & ~(size_t)255; return q; };
    float* h      = (float*)carve((size_t)NNODES * NO * 4);        // 20.48 MB
    float* huv    = (float*)carve((size_t)NNODES * 768 * 4);       // 61.44 MB
    float* Wcat   = (float*)carve((size_t)NL * 768 * NO * 4);      // 22.02 MB
    float* bcat   = (float*)carve((size_t)NL * 768 * 4);
    float* xpad   = (float*)carve((size_t)NNODES * KPAD * 4);      // 5.12 MB
    int*   offs   = (int*)carve((size_t)(NNODES + 1) * 4);
    int*   counts = (int*)carve((size_t)T2 * 4);                   // 3.2 MB
    int*   offs2  = (int*)carve((size_t)(T2 + 1) * 4);             // 3.2 MB
    int*   cur2   = (int*)carve((size_t)(T2 + 1) * 4);             // 3.2 MB
    int*   srcp   = (int*)carve((size_t)NEDGES * 4);
    float* efp    = (float*)carve((size_t)NEDGES * 4);
    float* sums   = (float*)carve((size_t)NGRAPHS * NO * 4);

    const int* src = ei;
    const int* dst = ei + NEDGES;

    // segmented CSR build: per-dst lists in ascending-src-block order
    hipMemsetAsync(counts, 0, (size_t)T2 * 4, stream);
    k_hist2<<<NEDGES / 256, 256, 0, stream>>>(src, dst, counts);
    k_scan2<<<1, 1024, 0, stream>>>(counts, offs2, cur2);
    k_offc<<<(NNODES + 256) / 256, 256, 0, stream>>>(offs2, offs);
    k_fill2<<<NEDGES / 256, 256, 0, stream>>>(src, dst, ef, cur2, srcp, efp);

    // layer-0 padded input + composed per-layer weights
    k_padx<<<(NNODES * KPAD + 255) / 256, 256, 0, stream>>>(x, xpad);
    k_prep<<<NL * 768, 256, 0, stream>>>(Wn0, bn0, We0, be0, Wm0, bm0,
                                         Wn, bn, We, be, Wm, bm, Wcat, bcat);

    // 28 layers
    for (int l = 0; l < NL; ++l) {
        const float* Ain = (l == 0) ? xpad : h;
        int K = (l == 0) ? KPAD : NO;
        dim3 grid(768 / BN, (NNODES + BM - 1) / BM);
        k_gemm<<<grid, 256, 0, stream>>>(Ain, Wcat + (size_t)l * 768 * NO, bcat + (size_t)l * 768,
                                         huv, NNODES, K);
        k_edge<<<NNODES / 4, 256, 0, stream>>>(huv, offs, srcp, efp, h);
    }

    // mean-pool via sorted ranges, then tiny final GEMM
    hipMemsetAsync(sums, 0, (size_t)NGRAPHS * NO * 4, stream);
    dim3 pg(NGRAPHS, 8);
    k_pool2<<<pg, 256, 0, stream>>>(h, batch, sums);
    k_final<<<NGRAPHS, 512, 0, stream>>>(sums, batch, Wlin, blin, out);
}

// Round 4
// 5876.876 us; speedup vs baseline: 1.7614x; 1.7614x over previous
//
#include <hip/hip_runtime.h>
#include <hip/hip_fp16.h>

#define NNODES 20000
#define NEDGES 640000
#define NGRAPHS 16
#define NO     256
#define NNF    58
#define KPAD   64
#define EMBD   512
#define NL     28

// ---------------- CSR build (once per launch, round-2 proven version) ----------------
__global__ __launch_bounds__(256) void k_hist(const int* __restrict__ dst, int* __restrict__ counts) {
    int e = blockIdx.x * 256 + threadIdx.x;
    if (e < NEDGES) atomicAdd(&counts[dst[e]], 1);
}

__global__ __launch_bounds__(256) void k_scan(const int* __restrict__ counts, int* __restrict__ offs) {
    __shared__ int part[256];
    int t = threadIdx.x;
    const int CH = (NNODES + 255) / 256;  // 79
    int base = t * CH;
    int s = 0;
    for (int i = 0; i < CH; ++i) { int idx = base + i; if (idx < NNODES) s += counts[idx]; }
    part[t] = s;
    __syncthreads();
    if (t == 0) { int acc = 0; for (int i = 0; i < 256; ++i) { int v = part[i]; part[i] = acc; acc += v; } }
    __syncthreads();
    int acc = part[t];
    for (int i = 0; i < CH; ++i) { int idx = base + i; if (idx < NNODES) { offs[idx] = acc; acc += counts[idx]; } }
    if (t == 255) offs[NNODES] = acc;
}

__global__ __launch_bounds__(256) void k_copy(const int* __restrict__ a, int* __restrict__ b, int n) {
    int i = blockIdx.x * 256 + threadIdx.x;
    if (i < n) b[i] = a[i];
}

__global__ __launch_bounds__(256) void k_fill(const int* __restrict__ src, const int* __restrict__ dst,
                                              const float* __restrict__ ef, int* __restrict__ cursor,
                                              int* __restrict__ srcp, float* __restrict__ efp) {
    int e = blockIdx.x * 256 + threadIdx.x;
    if (e < NEDGES) {
        int d = dst[e];
        int pos = atomicAdd(&cursor[d], 1);
        srcp[pos] = src[e];
        efp[pos]  = ef[e];
    }
}

// ---------------- layer-0 input pad: [20000][58] -> [20000][64] ----------------
__global__ __launch_bounds__(256) void k_padx(const float* __restrict__ x, float* __restrict__ xpad) {
    int i = blockIdx.x * 256 + threadIdx.x;
    if (i < NNODES * KPAD) {
        int r = i >> 6, c = i & 63;
        xpad[i] = (c < NNF) ? x[r * NNF + c] : 0.f;
    }
}

// ---------------- weight precompute ----------------
// Wcat layout: [NL][768][NO] row-major (layer 0 uses only first NNF cols, rest zero).
// rows 0..255 = Wn; 256..511 = SCL*(Wm*diag(We))@Wn; 512..767 = SCL*(Wm*diag(be))@Wn
// SCL = 2*log2(e) folded in so edge kernel uses exp2 directly.
#define SCL 2.8853900817779268f
__global__ __launch_bounds__(256) void k_prep(
    const float* __restrict__ Wn0, const float* __restrict__ bn0,
    const float* __restrict__ We0, const float* __restrict__ be0,
    const float* __restrict__ Wm0, const float* __restrict__ bm0,
    const float* __restrict__ Wn,  const float* __restrict__ bn,
    const float* __restrict__ We,  const float* __restrict__ be,
    const float* __restrict__ Wm,  const float* __restrict__ bm,
    float* __restrict__ Wcat, float* __restrict__ bcat) {
    int l = blockIdx.x / 768;
    int r = blockIdx.x % 768;
    int k = threadIdx.x;  // 0..255
    const float *wn, *bnv, *wev, *bev, *wm, *bmv;
    int K;
    if (l == 0) { wn = Wn0; bnv = bn0; wev = We0; bev = be0; wm = Wm0; bmv = bm0; K = NNF; }
    else {
        int j = l - 1;
        wn = Wn + (size_t)j * NO * NO; bnv = bn + j * NO;
        wev = We + j * NO;             bev = be + j * NO;
        wm = Wm + (size_t)j * NO * NO; bmv = bm + j * NO;
        K = NO;
    }
    float* Wout = Wcat + ((size_t)l * 768 + r) * NO;
    float* bout = bcat + l * 768 + r;
    if (r < NO) {
        if (k < K) Wout[k] = wn[(size_t)r * K + k];
        else       Wout[k] = 0.f;
        if (k == 0) *bout = bnv[r];
        return;
    }
    int i = (r < 512) ? r - 256 : r - 512;
    const float* scale = (r < 512) ? wev : bev;
    __shared__ float coeff[NO];
    coeff[k] = wm[(size_t)i * NO + k] * scale[k];
    __syncthreads();
    float acc = 0.f;
    if (k < K) {
        for (int j = 0; j < NO; ++j) acc += coeff[j] * wn[(size_t)j * K + k];
        Wout[k] = acc * SCL;
    } else Wout[k] = 0.f;
    if (k == 0) {
        float b = 0.f;
        for (int j = 0; j < NO; ++j) b += coeff[j] * bnv[j];
        if (r >= 512) b += bmv[i];
        *bout = b * SCL;
    }
}

// ---------------- fused layer GEMM: [hn | u | v] = A[M x K] @ W[768 x K].T + bias ----------------
// hn (cols 0..255) -> HN fp32 [M][256]; u/v (cols 256..767) -> UV fp16 [M][512],
// interleaved: u_i -> 8*(i>>2)+(i&3), v_i -> +4 (per-lane 16B gather granule).
#define BM 128
#define BN 64
#define BK 16
__global__ __launch_bounds__(256) void k_gemm(const float* __restrict__ A, const float* __restrict__ W,
                                              const float* __restrict__ bias,
                                              float* __restrict__ HN, __half* __restrict__ UV,
                                              int M, int K) {
    __shared__ float sA[BK][BM + 4];
    __shared__ float sB[BK][BN + 4];
    int bn0 = blockIdx.x * BN;
    int bm0 = blockIdx.y * BM;
    int t = threadIdx.x;
    int tx = t & 15, ty = t >> 4;
    float acc[8][4] = {};
    for (int k0 = 0; k0 < K; k0 += BK) {
        #pragma unroll
        for (int rep = 0; rep < 2; ++rep) {
            int idx = t + rep * 256;
            int r = idx >> 2, cq = (idx & 3) * 4;
            int gr = bm0 + r;
            float4 a4 = {0.f, 0.f, 0.f, 0.f};
            if (gr < M) a4 = *(const float4*)(A + (size_t)gr * K + k0 + cq);
            sA[cq + 0][r] = a4.x; sA[cq + 1][r] = a4.y; sA[cq + 2][r] = a4.z; sA[cq + 3][r] = a4.w;
        }
        {
            int r = t >> 2, cq = (t & 3) * 4;
            float4 b4 = *(const float4*)(W + (size_t)(bn0 + r) * NO + k0 + cq);
            sB[cq + 0][r] = b4.x; sB[cq + 1][r] = b4.y; sB[cq + 2][r] = b4.z; sB[cq + 3][r] = b4.w;
        }
        __syncthreads();
        #pragma unroll
        for (int kk = 0; kk < BK; ++kk) {
            float a[8], b[4];
            *(float4*)a       = *(const float4*)&sA[kk][ty * 8];
            *(float4*)(a + 4) = *(const float4*)&sA[kk][ty * 8 + 4];
            *(float4*)b       = *(const float4*)&sB[kk][tx * 4];
            #pragma unroll
            for (int i = 0; i < 8; ++i)
                #pragma unroll
                for (int j = 0; j < 4; ++j) acc[i][j] += a[i] * b[j];
        }
        __syncthreads();
    }
    int n0 = bn0 + tx * 4;
    float4 bi = *(const float4*)(bias + n0);
    if (n0 < 256) {
        #pragma unroll
        for (int i = 0; i < 8; ++i) {
            int gr = bm0 + ty * 8 + i;
            if (gr >= M) continue;
            float4 o = {acc[i][0] + bi.x, acc[i][1] + bi.y, acc[i][2] + bi.z, acc[i][3] + bi.w};
            *(float4*)(HN + (size_t)gr * NO + n0) = o;
        }
    } else {
        int i0 = (n0 < 512) ? n0 - 256 : n0 - 512;
        int hoff = 8 * (i0 >> 2) + ((n0 < 512) ? 0 : 4);
        #pragma unroll
        for (int i = 0; i < 8; ++i) {
            int gr = bm0 + ty * 8 + i;
            if (gr >= M) continue;
            union { __half2 h2[2]; uint2 u; } pk;
            pk.h2[0] = __floats2half2_rn(acc[i][0] + bi.x, acc[i][1] + bi.y);
            pk.h2[1] = __floats2half2_rn(acc[i][2] + bi.z, acc[i][3] + bi.w);
            *(uint2*)(UV + (size_t)gr * 512 + hoff) = pk.u;
        }
    }
}

// ---------------- edge aggregation: wave-per-node, fp16 u/v gather ----------------
__global__ __launch_bounds__(256) void k_edge(const float* __restrict__ HN, const __half* __restrict__ UV,
                                              const int* __restrict__ offs,
                                              const int* __restrict__ srcp, const float* __restrict__ efp,
                                              float* __restrict__ hout) {
    int wv = threadIdx.x >> 6;
    int lane = threadIdx.x & 63;
    int n = blockIdx.x * 4 + wv;
    int e0 = offs[n], e1 = offs[n + 1];
    float a0 = 0.f, a1 = 0.f, a2 = 0.f, a3 = 0.f;
    for (int eb = e0; eb < e1; eb += 64) {
        int cnt = e1 - eb; if (cnt > 64) cnt = 64;
        int sv = 0; float fv = 0.f;
        if (lane < cnt) { sv = srcp[eb + lane]; fv = efp[eb + lane]; }
        #pragma unroll 4
        for (int i = 0; i < cnt; ++i) {
            int ss = __shfl(sv, i);
            float ff = __shfl(fv, i);
            float4 raw = *(const float4*)(UV + (size_t)ss * 512 + lane * 8);
            const __half2* hp = (const __half2*)&raw;
            float2 u01 = __half22float2(hp[0]);
            float2 u23 = __half22float2(hp[1]);
            float2 v01 = __half22float2(hp[2]);
            float2 v23 = __half22float2(hp[3]);
            float g0 = exp2f(fmaf(ff, u01.x, v01.x));
            float g1 = exp2f(fmaf(ff, u01.y, v01.y));
            float g2 = exp2f(fmaf(ff, u23.x, v23.x));
            float g3 = exp2f(fmaf(ff, u23.y, v23.y));
            a0 += 1.0f - 2.0f * __builtin_amdgcn_rcpf(g0 + 1.0f);
            a1 += 1.0f - 2.0f * __builtin_amdgcn_rcpf(g1 + 1.0f);
            a2 += 1.0f - 2.0f * __builtin_amdgcn_rcpf(g2 + 1.0f);
            a3 += 1.0f - 2.0f * __builtin_amdgcn_rcpf(g3 + 1.0f);
        }
    }
    float4 hn4 = *(const float4*)(HN + (size_t)n * NO + lane * 4);
    float4 o = {hn4.x + a0, hn4.y + a1, hn4.z + a2, hn4.w + a3};
    *(float4*)(hout + (size_t)n * NO + lane * 4) = o;
}

// ---------------- pooling via sorted-batch ranges ----------------
__device__ __forceinline__ int lower_bound_g(const int* __restrict__ batch, int target) {
    int lo = 0, hi = NNODES;
    while (lo < hi) { int mid = (lo + hi) >> 1; if (batch[mid] < target) lo = mid + 1; else hi = mid; }
    return lo;
}

__global__ __launch_bounds__(256) void k_pool2(const float* __restrict__ h, const int* __restrict__ batch,
                                               float* __restrict__ sums) {
    int g = blockIdx.x, chunk = blockIdx.y;
    __shared__ int sh[2];
    if (threadIdx.x < 2) sh[threadIdx.x] = lower_bound_g(batch, g + (int)threadIdx.x);
    __syncthreads();
    int lo = sh[0], hi = sh[1];
    float acc = 0.f;
    for (int r = lo + chunk; r < hi; r += 8)
        acc += h[(size_t)r * NO + threadIdx.x];
    atomicAdd(&sums[g * NO + threadIdx.x], acc);
}

__global__ __launch_bounds__(512) void k_final(const float* __restrict__ sums, const int* __restrict__ batch,
                                               const float* __restrict__ Wlin, const float* __restrict__ blin,
                                               float* __restrict__ out) {
    int g = blockIdx.x, t = threadIdx.x;
    __shared__ int sh[2];
    __shared__ float m[NO];
    if (t < 2) sh[t] = lower_bound_g(batch, g + t);
    __syncthreads();
    float inv = 1.f / (float)(sh[1] - sh[0]);
    if (t < NO) m[t] = sums[g * NO + t] * inv;
    __syncthreads();
    float acc = blin[t];
    for (int k = 0; k < NO; ++k) acc += m[k] * Wlin[(size_t)t * NO + k];
    out[(size_t)g * EMBD + t] = acc;
}

extern "C" void kernel_launch(void* const* d_in, const int* in_sizes, int n_in,
                              void* d_out, int out_size, void* d_ws, size_t ws_size,
                              hipStream_t stream) {
    const float* x     = (const float*)d_in[0];
    const int*   ei    = (const int*)d_in[1];
    const float* ef    = (const float*)d_in[2];
    const int*   batch = (const int*)d_in[3];
    const float* Wn0 = (const float*)d_in[4];
    const float* bn0 = (const float*)d_in[5];
    const float* We0 = (const float*)d_in[6];
    const float* be0 = (const float*)d_in[7];
    const float* Wm0 = (const float*)d_in[8];
    const float* bm0 = (const float*)d_in[9];
    const float* Wn  = (const float*)d_in[10];
    const float* bn  = (const float*)d_in[11];
    const float* We  = (const float*)d_in[12];
    const float* be  = (const float*)d_in[13];
    const float* Wm  = (const float*)d_in[14];
    const float* bm  = (const float*)d_in[15];
    const float* Wlin = (const float*)d_in[16];
    const float* blin = (const float*)d_in[17];
    float* out = (float*)d_out;

    // workspace carve (256B aligned slices)
    char* p = (char*)d_ws;
    auto carve = [&](size_t bytes) { char* q = p; p += (bytes + 255) & ~(size_t)255; return q; };
    float*  h    = (float*)carve((size_t)NNODES * NO * 4);        // 20.48 MB
    float*  HN   = (float*)carve((size_t)NNODES * NO * 4);        // 20.48 MB
    __half* UV   = (__half*)carve((size_t)NNODES * 512 * 2);      // 20.48 MB
    float*  Wcat = (float*)carve((size_t)NL * 768 * NO * 4);      // 22.02 MB
    float*  bcat = (float*)carve((size_t)NL * 768 * 4);
    float*  xpad = (float*)carve((size_t)NNODES * KPAD * 4);      // 5.12 MB
    int*    offs = (int*)carve((size_t)(NNODES + 1) * 4);
    int*    cur  = (int*)carve((size_t)NNODES * 4);
    int*    srcp = (int*)carve((size_t)NEDGES * 4);
    float*  efp  = (float*)carve((size_t)NEDGES * 4);
    float*  sums = (float*)carve((size_t)NGRAPHS * NO * 4);

    const int* src = ei;
    const int* dst = ei + NEDGES;

    // CSR build (simple per-dst, unsorted)
    hipMemsetAsync(cur, 0, (size_t)NNODES * 4, stream);
    k_hist<<<NEDGES / 256, 256, 0, stream>>>(dst, cur);
    k_scan<<<1, 256, 0, stream>>>(cur, offs);
    k_copy<<<(NNODES + 255) / 256, 256, 0, stream>>>(offs, cur, NNODES);
    k_fill<<<NEDGES / 256, 256, 0, stream>>>(src, dst, ef, cur, srcp, efp);

    // layer-0 padded input + composed per-layer weights
    k_padx<<<(NNODES * KPAD + 255) / 256, 256, 0, stream>>>(x, xpad);
    k_prep<<<NL * 768, 256, 0, stream>>>(Wn0, bn0, We0, be0, Wm0, bm0,
                                         Wn, bn, We, be, Wm, bm, Wcat, bcat);

    // 28 layers
    for (int l = 0; l < NL; ++l) {
        const float* Ain = (l == 0) ? xpad : h;
        int K = (l == 0) ? KPAD : NO;
        dim3 grid(768 / BN, (NNODES + BM - 1) / BM);
        k_gemm<<<grid, 256, 0, stream>>>(Ain, Wcat + (size_t)l * 768 * NO, bcat + (size_t)l * 768,
                                         HN, UV, NNODES, K);
        k_edge<<<NNODES / 4, 256, 0, stream>>>(HN, UV, offs, srcp, efp, h);
    }

    // mean-pool via sorted ranges, then tiny final GEMM
    hipMemsetAsync(sums, 0, (size_t)NGRAPHS * NO * 4, stream);
    dim3 pg(NGRAPHS, 8);
    k_pool2<<<pg, 256, 0, stream>>>(h, batch, sums);
    k_final<<<NGRAPHS, 512, 0, stream>>>(sums, batch, Wlin, blin, out);
}

// Round 5
// 5733.615 us; speedup vs baseline: 1.8054x; 1.0250x over previous
//
#include <hip/hip_runtime.h>
#include <hip/hip_fp16.h>

#define NNODES 20000
#define NEDGES 640000
#define NGRAPHS 16
#define NO     256
#define NNF    58
#define KPAD   64
#define EMBD   512
#define NL     28

// ---------------- CSR build (once per launch) ----------------
__global__ __launch_bounds__(256) void k_hist(const int* __restrict__ dst, int* __restrict__ counts) {
    int e = blockIdx.x * 256 + threadIdx.x;
    if (e < NEDGES) atomicAdd(&counts[dst[e]], 1);
}

__global__ __launch_bounds__(256) void k_scan(const int* __restrict__ counts, int* __restrict__ offs) {
    __shared__ int part[256];
    int t = threadIdx.x;
    const int CH = (NNODES + 255) / 256;  // 79
    int base = t * CH;
    int s = 0;
    for (int i = 0; i < CH; ++i) { int idx = base + i; if (idx < NNODES) s += counts[idx]; }
    part[t] = s;
    __syncthreads();
    if (t == 0) { int acc = 0; for (int i = 0; i < 256; ++i) { int v = part[i]; part[i] = acc; acc += v; } }
    __syncthreads();
    int acc = part[t];
    for (int i = 0; i < CH; ++i) { int idx = base + i; if (idx < NNODES) { offs[idx] = acc; acc += counts[idx]; } }
    if (t == 255) offs[NNODES] = acc;
}

__global__ __launch_bounds__(256) void k_copy(const int* __restrict__ a, int* __restrict__ b, int n) {
    int i = blockIdx.x * 256 + threadIdx.x;
    if (i < n) b[i] = a[i];
}

__global__ __launch_bounds__(256) void k_fill(const int* __restrict__ src, const int* __restrict__ dst,
                                              const float* __restrict__ ef, int* __restrict__ cursor,
                                              int* __restrict__ srcp, float* __restrict__ efp) {
    int e = blockIdx.x * 256 + threadIdx.x;
    if (e < NEDGES) {
        int d = dst[e];
        int pos = atomicAdd(&cursor[d], 1);
        srcp[pos] = src[e];
        efp[pos]  = ef[e];
    }
}

// ---------------- layer-0 input pad: [20000][58] -> [20000][64] ----------------
__global__ __launch_bounds__(256) void k_padx(const float* __restrict__ x, float* __restrict__ xpad) {
    int i = blockIdx.x * 256 + threadIdx.x;
    if (i < NNODES * KPAD) {
        int r = i >> 6, c = i & 63;
        xpad[i] = (c < NNF) ? x[r * NNF + c] : 0.f;
    }
}

// ---------------- weight precompute ----------------
// Wcat layout: [NL][768][NO] row-major (layer 0 uses only first NNF cols, rest zero).
// rows 0..255 = Wn; 256..511 = SCL*(Wm*diag(We))@Wn; 512..767 = SCL*(Wm*diag(be))@Wn
#define SCL 2.8853900817779268f

// A: plain copy of Wn rows (and bn biases) into rows 0..255
__global__ __launch_bounds__(256) void k_prepA(
    const float* __restrict__ Wn0, const float* __restrict__ bn0,
    const float* __restrict__ Wn,  const float* __restrict__ bn,
    float* __restrict__ Wcat, float* __restrict__ bcat) {
    int gid = blockIdx.x * 256 + threadIdx.x;
    if (gid >= NL * NO * NO) return;
    int l = gid / (NO * NO);
    int rem = gid % (NO * NO);
    int r = rem / NO, k = rem % NO;
    float w;
    if (l == 0) w = (k < NNF) ? Wn0[r * NNF + k] : 0.f;
    else        w = Wn[(size_t)(l - 1) * NO * NO + r * NO + k];
    Wcat[((size_t)l * 768 + r) * NO + k] = w;
    if (k == 0) bcat[l * 768 + r] = (l == 0) ? bn0[r] : bn[(l - 1) * NO + r];
}

// B: rows 256..767 — 32 output rows per block, coeff staged in LDS, 32 FMA per Wn load
__global__ __launch_bounds__(256) void k_prepB(
    const float* __restrict__ Wn0, const float* __restrict__ bn0,
    const float* __restrict__ We0, const float* __restrict__ be0,
    const float* __restrict__ Wm0, const float* __restrict__ bm0,
    const float* __restrict__ Wn,  const float* __restrict__ bn,
    const float* __restrict__ We,  const float* __restrict__ be,
    const float* __restrict__ Wm,  const float* __restrict__ bm,
    float* __restrict__ Wcat, float* __restrict__ bcat) {
    int l = blockIdx.x >> 4;            // 28 layers
    int rr0 = (blockIdx.x & 15) * 32;   // 512 rows / 32
    int k = threadIdx.x;                // 0..255
    const float *wn, *bnv, *wev, *bev, *wm, *bmv;
    int K;
    if (l == 0) { wn = Wn0; bnv = bn0; wev = We0; bev = be0; wm = Wm0; bmv = bm0; K = NNF; }
    else {
        int j = l - 1;
        wn = Wn + (size_t)j * NO * NO; bnv = bn + j * NO;
        wev = We + j * NO;             bev = be + j * NO;
        wm = Wm + (size_t)j * NO * NO; bmv = bm + j * NO;
        K = NO;
    }
    __shared__ float coeff[32][NO + 1];   // pad: bias pass reads column-wise
    for (int q = 0; q < 32; ++q) {
        int rr = rr0 + q;
        int i = rr & 255;
        const float* scale = (rr < 256) ? wev : bev;
        coeff[q][k] = wm[(size_t)i * NO + k] * scale[k];
    }
    __syncthreads();
    float acc[32] = {};
    if (k < K) {
        for (int j = 0; j < NO; ++j) {
            float wv = wn[(size_t)j * K + k];
            #pragma unroll
            for (int q = 0; q < 32; ++q) acc[q] += coeff[q][j] * wv;
        }
    }
    for (int q = 0; q < 32; ++q)
        Wcat[((size_t)l * 768 + 256 + rr0 + q) * NO + k] = (k < K) ? acc[q] * SCL : 0.f;
    if (k < 32) {
        int rr = rr0 + k;
        int i = rr & 255;
        float b = 0.f;
        for (int j = 0; j < NO; ++j) b += coeff[k][j] * bnv[j];
        if (rr >= 256) b += bmv[i];
        bcat[l * 768 + 256 + rr] = b * SCL;
    }
}

// ---------------- fused layer GEMM: [hn | u | v] = A[M x K] @ W[768 x K].T + bias ----------------
// 128x128 tile, 8x8 acc. hn (cols 0..255) -> HN fp32; u/v (cols 256..767) -> UV fp16 interleaved
// (u_i -> 8*(i>>2)+(i&3), v_i -> +4; per-lane 16B gather granule).
#define BM 128
#define BN 128
#define BK 16
__global__ __launch_bounds__(256) void k_gemm(const float* __restrict__ A, const float* __restrict__ W,
                                              const float* __restrict__ bias,
                                              float* __restrict__ HN, __half* __restrict__ UV,
                                              int M, int K) {
    __shared__ float sA[BK][BM + 4];
    __shared__ float sB[BK][BN + 4];
    int bn0 = blockIdx.x * BN;
    int bm0 = blockIdx.y * BM;
    int t = threadIdx.x;
    int tx = t & 15, ty = t >> 4;
    float acc[8][8] = {};
    for (int k0 = 0; k0 < K; k0 += BK) {
        #pragma unroll
        for (int rep = 0; rep < 2; ++rep) {
            int idx = t + rep * 256;             // 0..511
            int r = idx >> 2, cq = (idx & 3) * 4;
            int gr = bm0 + r;
            float4 a4 = {0.f, 0.f, 0.f, 0.f};
            if (gr < M) a4 = *(const float4*)(A + (size_t)gr * K + k0 + cq);
            sA[cq + 0][r] = a4.x; sA[cq + 1][r] = a4.y; sA[cq + 2][r] = a4.z; sA[cq + 3][r] = a4.w;
        }
        #pragma unroll
        for (int rep = 0; rep < 2; ++rep) {
            int idx = t + rep * 256;
            int r = idx >> 2, cq = (idx & 3) * 4;
            float4 b4 = *(const float4*)(W + (size_t)(bn0 + r) * NO + k0 + cq);
            sB[cq + 0][r] = b4.x; sB[cq + 1][r] = b4.y; sB[cq + 2][r] = b4.z; sB[cq + 3][r] = b4.w;
        }
        __syncthreads();
        #pragma unroll
        for (int kk = 0; kk < BK; ++kk) {
            float a[8], b[8];
            *(float4*)a       = *(const float4*)&sA[kk][ty * 8];
            *(float4*)(a + 4) = *(const float4*)&sA[kk][ty * 8 + 4];
            *(float4*)b       = *(const float4*)&sB[kk][tx * 8];
            *(float4*)(b + 4) = *(const float4*)&sB[kk][tx * 8 + 4];
            #pragma unroll
            for (int i = 0; i < 8; ++i)
                #pragma unroll
                for (int j = 0; j < 8; ++j) acc[i][j] += a[i] * b[j];
        }
        __syncthreads();
    }
    int n0 = bn0 + tx * 8;   // 8 consecutive output cols, never straddles a 256-boundary
    float bi[8];
    *(float4*)bi       = *(const float4*)(bias + n0);
    *(float4*)(bi + 4) = *(const float4*)(bias + n0 + 4);
    if (n0 < 256) {
        #pragma unroll
        for (int i = 0; i < 8; ++i) {
            int gr = bm0 + ty * 8 + i;
            if (gr >= M) continue;
            float4 o0 = {acc[i][0] + bi[0], acc[i][1] + bi[1], acc[i][2] + bi[2], acc[i][3] + bi[3]};
            float4 o1 = {acc[i][4] + bi[4], acc[i][5] + bi[5], acc[i][6] + bi[6], acc[i][7] + bi[7]};
            *(float4*)(HN + (size_t)gr * NO + n0)     = o0;
            *(float4*)(HN + (size_t)gr * NO + n0 + 4) = o1;
        }
    } else {
        int i0 = (n0 < 512) ? n0 - 256 : n0 - 512;   // multiple of 8
        int sel = (n0 < 512) ? 0 : 4;
        int base = 2 * i0 + sel;                      // 8*(i0>>2)+sel
        #pragma unroll
        for (int i = 0; i < 8; ++i) {
            int gr = bm0 + ty * 8 + i;
            if (gr >= M) continue;
            union { __half2 h2[2]; uint2 u; } p0, p1;
            p0.h2[0] = __floats2half2_rn(acc[i][0] + bi[0], acc[i][1] + bi[1]);
            p0.h2[1] = __floats2half2_rn(acc[i][2] + bi[2], acc[i][3] + bi[3]);
            p1.h2[0] = __floats2half2_rn(acc[i][4] + bi[4], acc[i][5] + bi[5]);
            p1.h2[1] = __floats2half2_rn(acc[i][6] + bi[6], acc[i][7] + bi[7]);
            *(uint2*)(UV + (size_t)gr * 512 + base)     = p0.u;
            *(uint2*)(UV + (size_t)gr * 512 + base + 8) = p1.u;
        }
    }
}

// ---------------- edge aggregation: wave-per-node, fp16 u/v gather ----------------
__global__ __launch_bounds__(256) void k_edge(const float* __restrict__ HN, const __half* __restrict__ UV,
                                              const int* __restrict__ offs,
                                              const int* __restrict__ srcp, const float* __restrict__ efp,
                                              float* __restrict__ hout) {
    int wv = threadIdx.x >> 6;
    int lane = threadIdx.x & 63;
    int n = blockIdx.x * 4 + wv;
    int e0 = offs[n], e1 = offs[n + 1];
    float a0 = 0.f, a1 = 0.f, a2 = 0.f, a3 = 0.f;
    for (int eb = e0; eb < e1; eb += 64) {
        int cnt = e1 - eb; if (cnt > 64) cnt = 64;
        int sv = 0; float fv = 0.f;
        if (lane < cnt) { sv = srcp[eb + lane]; fv = efp[eb + lane]; }
        #pragma unroll 4
        for (int i = 0; i < cnt; ++i) {
            int ss = __shfl(sv, i);
            float ff = __shfl(fv, i);
            float4 raw = *(const float4*)(UV + (size_t)ss * 512 + lane * 8);
            const __half2* hp = (const __half2*)&raw;
            float2 u01 = __half22float2(hp[0]);
            float2 u23 = __half22float2(hp[1]);
            float2 v01 = __half22float2(hp[2]);
            float2 v23 = __half22float2(hp[3]);
            float g0 = exp2f(fmaf(ff, u01.x, v01.x));
            float g1 = exp2f(fmaf(ff, u01.y, v01.y));
            float g2 = exp2f(fmaf(ff, u23.x, v23.x));
            float g3 = exp2f(fmaf(ff, u23.y, v23.y));
            a0 += 1.0f - 2.0f * __builtin_amdgcn_rcpf(g0 + 1.0f);
            a1 += 1.0f - 2.0f * __builtin_amdgcn_rcpf(g1 + 1.0f);
            a2 += 1.0f - 2.0f * __builtin_amdgcn_rcpf(g2 + 1.0f);
            a3 += 1.0f - 2.0f * __builtin_amdgcn_rcpf(g3 + 1.0f);
        }
    }
    float4 hn4 = *(const float4*)(HN + (size_t)n * NO + lane * 4);
    float4 o = {hn4.x + a0, hn4.y + a1, hn4.z + a2, hn4.w + a3};
    *(float4*)(hout + (size_t)n * NO + lane * 4) = o;
}

// ---------------- pooling via sorted-batch ranges ----------------
__device__ __forceinline__ int lower_bound_g(const int* __restrict__ batch, int target) {
    int lo = 0, hi = NNODES;
    while (lo < hi) { int mid = (lo + hi) >> 1; if (batch[mid] < target) lo = mid + 1; else hi = mid; }
    return lo;
}

__global__ __launch_bounds__(256) void k_pool2(const float* __restrict__ h, const int* __restrict__ batch,
                                               float* __restrict__ sums) {
    int g = blockIdx.x, chunk = blockIdx.y;
    __shared__ int sh[2];
    if (threadIdx.x < 2) sh[threadIdx.x] = lower_bound_g(batch, g + (int)threadIdx.x);
    __syncthreads();
    int lo = sh[0], hi = sh[1];
    float acc = 0.f;
    for (int r = lo + chunk; r < hi; r += 8)
        acc += h[(size_t)r * NO + threadIdx.x];
    atomicAdd(&sums[g * NO + threadIdx.x], acc);
}

__global__ __launch_bounds__(512) void k_final(const float* __restrict__ sums, const int* __restrict__ batch,
                                               const float* __restrict__ Wlin, const float* __restrict__ blin,
                                               float* __restrict__ out) {
    int g = blockIdx.x, t = threadIdx.x;
    __shared__ int sh[2];
    __shared__ float m[NO];
    if (t < 2) sh[t] = lower_bound_g(batch, g + t);
    __syncthreads();
    float inv = 1.f / (float)(sh[1] - sh[0]);
    if (t < NO) m[t] = sums[g * NO + t] * inv;
    __syncthreads();
    float acc = blin[t];
    for (int k = 0; k < NO; ++k) acc += m[k] * Wlin[(size_t)t * NO + k];
    out[(size_t)g * EMBD + t] = acc;
}

extern "C" void kernel_launch(void* const* d_in, const int* in_sizes, int n_in,
                              void* d_out, int out_size, void* d_ws, size_t ws_size,
                              hipStream_t stream) {
    const float* x     = (const float*)d_in[0];
    const int*   ei    = (const int*)d_in[1];
    const float* ef    = (const float*)d_in[2];
    const int*   batch = (const int*)d_in[3];
    const float* Wn0 = (const float*)d_in[4];
    const float* bn0 = (const float*)d_in[5];
    const float* We0 = (const float*)d_in[6];
    const float* be0 = (const float*)d_in[7];
    const float* Wm0 = (const float*)d_in[8];
    const float* bm0 = (const float*)d_in[9];
    const float* Wn  = (const float*)d_in[10];
    const float* bn  = (const float*)d_in[11];
    const float* We  = (const float*)d_in[12];
    const float* be  = (const float*)d_in[13];
    const float* Wm  = (const float*)d_in[14];
    const float* bm  = (const float*)d_in[15];
    const float* Wlin = (const float*)d_in[16];
    const float* blin = (const float*)d_in[17];
    float* out = (float*)d_out;

    // workspace carve (256B aligned slices)
    char* p = (char*)d_ws;
    auto carve = [&](size_t bytes) { char* q = p; p += (bytes + 255) & ~(size_t)255; return q; };
    float*  h    = (float*)carve((size_t)NNODES * NO * 4);        // 20.48 MB
    float*  HN   = (float*)carve((size_t)NNODES * NO * 4);        // 20.48 MB
    __half* UV   = (__half*)carve((size_t)NNODES * 512 * 2);      // 20.48 MB
    float*  Wcat = (float*)carve((size_t)NL * 768 * NO * 4);      // 22.02 MB
    float*  bcat = (float*)carve((size_t)NL * 768 * 4);
    float*  xpad = (float*)carve((size_t)NNODES * KPAD * 4);      // 5.12 MB
    int*    offs = (int*)carve((size_t)(NNODES + 1) * 4);
    int*    cur  = (int*)carve((size_t)NNODES * 4);
    int*    srcp = (int*)carve((size_t)NEDGES * 4);
    float*  efp  = (float*)carve((size_t)NEDGES * 4);
    float*  sums = (float*)carve((size_t)NGRAPHS * NO * 4);

    const int* src = ei;
    const int* dst = ei + NEDGES;

    // CSR build
    hipMemsetAsync(cur, 0, (size_t)NNODES * 4, stream);
    k_hist<<<NEDGES / 256, 256, 0, stream>>>(dst, cur);
    k_scan<<<1, 256, 0, stream>>>(cur, offs);
    k_copy<<<(NNODES + 255) / 256, 256, 0, stream>>>(offs, cur, NNODES);
    k_fill<<<NEDGES / 256, 256, 0, stream>>>(src, dst, ef, cur, srcp, efp);

    // layer-0 padded input + composed per-layer weights
    k_padx<<<(NNODES * KPAD + 255) / 256, 256, 0, stream>>>(x, xpad);
    k_prepA<<<(NL * NO * NO + 255) / 256, 256, 0, stream>>>(Wn0, bn0, Wn, bn, Wcat, bcat);
    k_prepB<<<NL * 16, 256, 0, stream>>>(Wn0, bn0, We0, be0, Wm0, bm0,
                                         Wn, bn, We, be, Wm, bm, Wcat, bcat);

    // 28 layers
    for (int l = 0; l < NL; ++l) {
        const float* Ain = (l == 0) ? xpad : h;
        int K = (l == 0) ? KPAD : NO;
        dim3 grid(768 / BN, (NNODES + BM - 1) / BM);
        k_gemm<<<grid, 256, 0, stream>>>(Ain, Wcat + (size_t)l * 768 * NO, bcat + (size_t)l * 768,
                                         HN, UV, NNODES, K);
        k_edge<<<NNODES / 4, 256, 0, stream>>>(HN, UV, offs, srcp, efp, h);
    }

    // mean-pool via sorted ranges, then tiny final GEMM
    hipMemsetAsync(sums, 0, (size_t)NGRAPHS * NO * 4, stream);
    dim3 pg(NGRAPHS, 8);
    k_pool2<<<pg, 256, 0, stream>>>(h, batch, sums);
    k_final<<<NGRAPHS, 512, 0, stream>>>(sums, batch, Wlin, blin, out);
}

// Round 6
// 5627.457 us; speedup vs baseline: 1.8394x; 1.0189x over previous
//
#include <hip/hip_runtime.h>
#include <hip/hip_fp16.h>

#define NNODES 20000
#define NEDGES 640000
#define NGRAPHS 16
#define NO     256
#define NNF    58
#define KPAD   64
#define EMBD   512
#define NL     28

// ---------------- CSR build (once per launch) ----------------
__global__ __launch_bounds__(256) void k_hist(const int* __restrict__ dst, int* __restrict__ counts) {
    int e = blockIdx.x * 256 + threadIdx.x;
    if (e < NEDGES) atomicAdd(&counts[dst[e]], 1);
}

__global__ __launch_bounds__(256) void k_scan(const int* __restrict__ counts, int* __restrict__ offs) {
    __shared__ int part[256];
    int t = threadIdx.x;
    const int CH = (NNODES + 255) / 256;  // 79
    int base = t * CH;
    int s = 0;
    for (int i = 0; i < CH; ++i) { int idx = base + i; if (idx < NNODES) s += counts[idx]; }
    part[t] = s;
    __syncthreads();
    if (t == 0) { int acc = 0; for (int i = 0; i < 256; ++i) { int v = part[i]; part[i] = acc; acc += v; } }
    __syncthreads();
    int acc = part[t];
    for (int i = 0; i < CH; ++i) { int idx = base + i; if (idx < NNODES) { offs[idx] = acc; acc += counts[idx]; } }
    if (t == 255) offs[NNODES] = acc;
}

__global__ __launch_bounds__(256) void k_copy(const int* __restrict__ a, int* __restrict__ b, int n) {
    int i = blockIdx.x * 256 + threadIdx.x;
    if (i < n) b[i] = a[i];
}

__global__ __launch_bounds__(256) void k_fill(const int* __restrict__ src, const int* __restrict__ dst,
                                              const float* __restrict__ ef, int* __restrict__ cursor,
                                              int* __restrict__ srcp, float* __restrict__ efp) {
    int e = blockIdx.x * 256 + threadIdx.x;
    if (e < NEDGES) {
        int d = dst[e];
        int pos = atomicAdd(&cursor[d], 1);
        srcp[pos] = src[e];
        efp[pos]  = ef[e];
    }
}

// ---------------- layer-0 input pad: [20000][58] -> [20000][64] ----------------
__global__ __launch_bounds__(256) void k_padx(const float* __restrict__ x, float* __restrict__ xpad) {
    int i = blockIdx.x * 256 + threadIdx.x;
    if (i < NNODES * KPAD) {
        int r = i >> 6, c = i & 63;
        xpad[i] = (c < NNF) ? x[r * NNF + c] : 0.f;
    }
}

// ---------------- weight precompute ----------------
// Wcat layout: [NL][768][NO] row-major (layer 0 uses only first NNF cols, rest zero).
// rows 0..255 = Wn; 256..511 = SCL*(Wm*diag(We))@Wn; 512..767 = SCL*(Wm*diag(be))@Wn
#define SCL 2.8853900817779268f

// A: plain copy of Wn rows (and bn biases) into rows 0..255
__global__ __launch_bounds__(256) void k_prepA(
    const float* __restrict__ Wn0, const float* __restrict__ bn0,
    const float* __restrict__ Wn,  const float* __restrict__ bn,
    float* __restrict__ Wcat, float* __restrict__ bcat) {
    int gid = blockIdx.x * 256 + threadIdx.x;
    if (gid >= NL * NO * NO) return;
    int l = gid / (NO * NO);
    int rem = gid % (NO * NO);
    int r = rem / NO, k = rem % NO;
    float w;
    if (l == 0) w = (k < NNF) ? Wn0[r * NNF + k] : 0.f;
    else        w = Wn[(size_t)(l - 1) * NO * NO + r * NO + k];
    Wcat[((size_t)l * 768 + r) * NO + k] = w;
    if (k == 0) bcat[l * 768 + r] = (l == 0) ? bn0[r] : bn[(l - 1) * NO + r];
}

// B: rows 256..767 — 32 output rows per block, coeff staged in LDS, 32 FMA per Wn load
__global__ __launch_bounds__(256) void k_prepB(
    const float* __restrict__ Wn0, const float* __restrict__ bn0,
    const float* __restrict__ We0, const float* __restrict__ be0,
    const float* __restrict__ Wm0, const float* __restrict__ bm0,
    const float* __restrict__ Wn,  const float* __restrict__ bn,
    const float* __restrict__ We,  const float* __restrict__ be,
    const float* __restrict__ Wm,  const float* __restrict__ bm,
    float* __restrict__ Wcat, float* __restrict__ bcat) {
    int l = blockIdx.x >> 4;            // 28 layers
    int rr0 = (blockIdx.x & 15) * 32;   // 512 rows / 32
    int k = threadIdx.x;                // 0..255
    const float *wn, *bnv, *wev, *bev, *wm, *bmv;
    int K;
    if (l == 0) { wn = Wn0; bnv = bn0; wev = We0; bev = be0; wm = Wm0; bmv = bm0; K = NNF; }
    else {
        int j = l - 1;
        wn = Wn + (size_t)j * NO * NO; bnv = bn + j * NO;
        wev = We + j * NO;             bev = be + j * NO;
        wm = Wm + (size_t)j * NO * NO; bmv = bm + j * NO;
        K = NO;
    }
    __shared__ float coeff[32][NO + 1];   // pad: bias pass reads column-wise
    for (int q = 0; q < 32; ++q) {
        int rr = rr0 + q;
        int i = rr & 255;
        const float* scale = (rr < 256) ? wev : bev;
        coeff[q][k] = wm[(size_t)i * NO + k] * scale[k];
    }
    __syncthreads();
    float acc[32] = {};
    if (k < K) {
        for (int j = 0; j < NO; ++j) {
            float wv = wn[(size_t)j * K + k];
            #pragma unroll
            for (int q = 0; q < 32; ++q) acc[q] += coeff[q][j] * wv;
        }
    }
    for (int q = 0; q < 32; ++q)
        Wcat[((size_t)l * 768 + 256 + rr0 + q) * NO + k] = (k < K) ? acc[q] * SCL : 0.f;
    if (k < 32) {
        int rr = rr0 + k;
        int i = rr & 255;
        float b = 0.f;
        for (int j = 0; j < NO; ++j) b += coeff[k][j] * bnv[j];
        if (rr >= 256) b += bmv[i];
        bcat[l * 768 + 256 + rr] = b * SCL;
    }
}

// ---------------- fused layer GEMM: [hn | u | v] = A[M x K] @ W[768 x K].T + bias ----------------
// 128x128 tile, 8x8 acc. Per-thread cols: {tx*4..+3} and {64+tx*4..+3} (64-split kills the
// 4-way LDS bank wrap of tx*8 addressing: 64-float span = 2-way = free).
// hn (cols 0..255) -> HN fp32; u/v (cols 256..767) -> UV fp16 interleaved
// (u_i -> 8*(i>>2)+(i&3), v_i -> +4; per-lane 16B gather granule).
#define BM 128
#define BN 128
#define BK 16
__global__ __launch_bounds__(256) void k_gemm(const float* __restrict__ A, const float* __restrict__ W,
                                              const float* __restrict__ bias,
                                              float* __restrict__ HN, __half* __restrict__ UV,
                                              int M, int K) {
    __shared__ float sA[BK][BM + 4];
    __shared__ float sB[BK][BN + 4];
    int bn0 = blockIdx.x * BN;
    int bm0 = blockIdx.y * BM;
    int t = threadIdx.x;
    int tx = t & 15, ty = t >> 4;
    float acc[8][8] = {};
    for (int k0 = 0; k0 < K; k0 += BK) {
        #pragma unroll
        for (int rep = 0; rep < 2; ++rep) {
            int idx = t + rep * 256;             // 0..511
            int r = idx >> 2, cq = (idx & 3) * 4;
            int gr = bm0 + r;
            float4 a4 = {0.f, 0.f, 0.f, 0.f};
            if (gr < M) a4 = *(const float4*)(A + (size_t)gr * K + k0 + cq);
            sA[cq + 0][r] = a4.x; sA[cq + 1][r] = a4.y; sA[cq + 2][r] = a4.z; sA[cq + 3][r] = a4.w;
        }
        #pragma unroll
        for (int rep = 0; rep < 2; ++rep) {
            int idx = t + rep * 256;
            int r = idx >> 2, cq = (idx & 3) * 4;
            float4 b4 = *(const float4*)(W + (size_t)(bn0 + r) * NO + k0 + cq);
            sB[cq + 0][r] = b4.x; sB[cq + 1][r] = b4.y; sB[cq + 2][r] = b4.z; sB[cq + 3][r] = b4.w;
        }
        __syncthreads();
        #pragma unroll
        for (int kk = 0; kk < BK; ++kk) {
            float a[8], b[8];
            *(float4*)a       = *(const float4*)&sA[kk][ty * 8];
            *(float4*)(a + 4) = *(const float4*)&sA[kk][ty * 8 + 4];
            *(float4*)b       = *(const float4*)&sB[kk][tx * 4];
            *(float4*)(b + 4) = *(const float4*)&sB[kk][64 + tx * 4];
            #pragma unroll
            for (int i = 0; i < 8; ++i)
                #pragma unroll
                for (int j = 0; j < 8; ++j) acc[i][j] += a[i] * b[j];
        }
        __syncthreads();
    }
    // epilogue: two 4-col groups; each group lies fully within one region (hn/u/v)
    #pragma unroll
    for (int grp = 0; grp < 2; ++grp) {
        int n0 = bn0 + grp * 64 + tx * 4;
        int jb = grp * 4;
        float4 bi = *(const float4*)(bias + n0);
        if (n0 < 256) {
            #pragma unroll
            for (int i = 0; i < 8; ++i) {
                int gr = bm0 + ty * 8 + i;
                if (gr >= M) continue;
                float4 o = {acc[i][jb + 0] + bi.x, acc[i][jb + 1] + bi.y,
                            acc[i][jb + 2] + bi.z, acc[i][jb + 3] + bi.w};
                *(float4*)(HN + (size_t)gr * NO + n0) = o;
            }
        } else {
            int i0 = (n0 < 512) ? n0 - 256 : n0 - 512;   // multiple of 4
            int base = 2 * i0 + ((n0 < 512) ? 0 : 4);     // 8*(i0>>2)+sel
            #pragma unroll
            for (int i = 0; i < 8; ++i) {
                int gr = bm0 + ty * 8 + i;
                if (gr >= M) continue;
                union { __half2 h2[2]; uint2 u; } pk;
                pk.h2[0] = __floats2half2_rn(acc[i][jb + 0] + bi.x, acc[i][jb + 1] + bi.y);
                pk.h2[1] = __floats2half2_rn(acc[i][jb + 2] + bi.z, acc[i][jb + 3] + bi.w);
                *(uint2*)(UV + (size_t)gr * 512 + base) = pk.u;
            }
        }
    }
}

// ---------------- edge aggregation: wave-per-node, fp16 u/v gather ----------------
__global__ __launch_bounds__(256) void k_edge(const float* __restrict__ HN, const __half* __restrict__ UV,
                                              const int* __restrict__ offs,
                                              const int* __restrict__ srcp, const float* __restrict__ efp,
                                              float* __restrict__ hout) {
    int wv = threadIdx.x >> 6;
    int lane = threadIdx.x & 63;
    int n = blockIdx.x * 4 + wv;
    int e0 = offs[n], e1 = offs[n + 1];
    float a0 = 0.f, a1 = 0.f, a2 = 0.f, a3 = 0.f;
    for (int eb = e0; eb < e1; eb += 64) {
        int cnt = e1 - eb; if (cnt > 64) cnt = 64;
        int sv = 0; float fv = 0.f;
        if (lane < cnt) { sv = srcp[eb + lane]; fv = efp[eb + lane]; }
        #pragma unroll 4
        for (int i = 0; i < cnt; ++i) {
            int ss = __shfl(sv, i);
            float ff = __shfl(fv, i);
            float4 raw = *(const float4*)(UV + (size_t)ss * 512 + lane * 8);
            const __half2* hp = (const __half2*)&raw;
            float2 u01 = __half22float2(hp[0]);
            float2 u23 = __half22float2(hp[1]);
            float2 v01 = __half22float2(hp[2]);
            float2 v23 = __half22float2(hp[3]);
            float g0 = exp2f(fmaf(ff, u01.x, v01.x));
            float g1 = exp2f(fmaf(ff, u01.y, v01.y));
            float g2 = exp2f(fmaf(ff, u23.x, v23.x));
            float g3 = exp2f(fmaf(ff, u23.y, v23.y));
            a0 += 1.0f - 2.0f * __builtin_amdgcn_rcpf(g0 + 1.0f);
            a1 += 1.0f - 2.0f * __builtin_amdgcn_rcpf(g1 + 1.0f);
            a2 += 1.0f - 2.0f * __builtin_amdgcn_rcpf(g2 + 1.0f);
            a3 += 1.0f - 2.0f * __builtin_amdgcn_rcpf(g3 + 1.0f);
        }
    }
    float4 hn4 = *(const float4*)(HN + (size_t)n * NO + lane * 4);
    float4 o = {hn4.x + a0, hn4.y + a1, hn4.z + a2, hn4.w + a3};
    *(float4*)(hout + (size_t)n * NO + lane * 4) = o;
}

// ---------------- pooling via sorted-batch ranges ----------------
__device__ __forceinline__ int lower_bound_g(const int* __restrict__ batch, int target) {
    int lo = 0, hi = NNODES;
    while (lo < hi) { int mid = (lo + hi) >> 1; if (batch[mid] < target) lo = mid + 1; else hi = mid; }
    return lo;
}

__global__ __launch_bounds__(256) void k_pool2(const float* __restrict__ h, const int* __restrict__ batch,
                                               float* __restrict__ sums) {
    int g = blockIdx.x, chunk = blockIdx.y;
    __shared__ int sh[2];
    if (threadIdx.x < 2) sh[threadIdx.x] = lower_bound_g(batch, g + (int)threadIdx.x);
    __syncthreads();
    int lo = sh[0], hi = sh[1];
    float acc = 0.f;
    for (int r = lo + chunk; r < hi; r += 8)
        acc += h[(size_t)r * NO + threadIdx.x];
    atomicAdd(&sums[g * NO + threadIdx.x], acc);
}

__global__ __launch_bounds__(512) void k_final(const float* __restrict__ sums, const int* __restrict__ batch,
                                               const float* __restrict__ Wlin, const float* __restrict__ blin,
                                               float* __restrict__ out) {
    int g = blockIdx.x, t = threadIdx.x;
    __shared__ int sh[2];
    __shared__ float m[NO];
    if (t < 2) sh[t] = lower_bound_g(batch, g + t);
    __syncthreads();
    float inv = 1.f / (float)(sh[1] - sh[0]);
    if (t < NO) m[t] = sums[g * NO + t] * inv;
    __syncthreads();
    float acc = blin[t];
    for (int k = 0; k < NO; ++k) acc += m[k] * Wlin[(size_t)t * NO + k];
    out[(size_t)g * EMBD + t] = acc;
}

extern "C" void kernel_launch(void* const* d_in, const int* in_sizes, int n_in,
                              void* d_out, int out_size, void* d_ws, size_t ws_size,
                              hipStream_t stream) {
    const float* x     = (const float*)d_in[0];
    const int*   ei    = (const int*)d_in[1];
    const float* ef    = (const float*)d_in[2];
    const int*   batch = (const int*)d_in[3];
    const float* Wn0 = (const float*)d_in[4];
    const float* bn0 = (const float*)d_in[5];
    const float* We0 = (const float*)d_in[6];
    const float* be0 = (const float*)d_in[7];
    const float* Wm0 = (const float*)d_in[8];
    const float* bm0 = (const float*)d_in[9];
    const float* Wn  = (const float*)d_in[10];
    const float* bn  = (const float*)d_in[11];
    const float* We  = (const float*)d_in[12];
    const float* be  = (const float*)d_in[13];
    const float* Wm  = (const float*)d_in[14];
    const float* bm  = (const float*)d_in[15];
    const float* Wlin = (const float*)d_in[16];
    const float* blin = (const float*)d_in[17];
    float* out = (float*)d_out;

    // workspace carve (256B aligned slices)
    char* p = (char*)d_ws;
    auto carve = [&](size_t bytes) { char* q = p; p += (bytes + 255) & ~(size_t)255; return q; };
    float*  h    = (float*)carve((size_t)NNODES * NO * 4);        // 20.48 MB
    float*  HN   = (float*)carve((size_t)NNODES * NO * 4);        // 20.48 MB
    __half* UV   = (__half*)carve((size_t)NNODES * 512 * 2);      // 20.48 MB
    float*  Wcat = (float*)carve((size_t)NL * 768 * NO * 4);      // 22.02 MB
    float*  bcat = (float*)carve((size_t)NL * 768 * 4);
    float*  xpad = (float*)carve((size_t)NNODES * KPAD * 4);      // 5.12 MB
    int*    offs = (int*)carve((size_t)(NNODES + 1) * 4);
    int*    cur  = (int*)carve((size_t)NNODES * 4);
    int*    srcp = (int*)carve((size_t)NEDGES * 4);
    float*  efp  = (float*)carve((size_t)NEDGES * 4);
    float*  sums = (float*)carve((size_t)NGRAPHS * NO * 4);

    const int* src = ei;
    const int* dst = ei + NEDGES;

    // CSR build
    hipMemsetAsync(cur, 0, (size_t)NNODES * 4, stream);
    k_hist<<<NEDGES / 256, 256, 0, stream>>>(dst, cur);
    k_scan<<<1, 256, 0, stream>>>(cur, offs);
    k_copy<<<(NNODES + 255) / 256, 256, 0, stream>>>(offs, cur, NNODES);
    k_fill<<<NEDGES / 256, 256, 0, stream>>>(src, dst, ef, cur, srcp, efp);

    // layer-0 padded input + composed per-layer weights
    k_padx<<<(NNODES * KPAD + 255) / 256, 256, 0, stream>>>(x, xpad);
    k_prepA<<<(NL * NO * NO + 255) / 256, 256, 0, stream>>>(Wn0, bn0, Wn, bn, Wcat, bcat);
    k_prepB<<<NL * 16, 256, 0, stream>>>(Wn0, bn0, We0, be0, Wm0, bm0,
                                         Wn, bn, We, be, Wm, bm, Wcat, bcat);

    // 28 layers
    for (int l = 0; l < NL; ++l) {
        const float* Ain = (l == 0) ? xpad : h;
        int K = (l == 0) ? KPAD : NO;
        dim3 grid(768 / BN, (NNODES + BM - 1) / BM);
        k_gemm<<<grid, 256, 0, stream>>>(Ain, Wcat + (size_t)l * 768 * NO, bcat + (size_t)l * 768,
                                         HN, UV, NNODES, K);
        k_edge<<<NNODES / 4, 256, 0, stream>>>(HN, UV, offs, srcp, efp, h);
    }

    // mean-pool via sorted ranges, then tiny final GEMM
    hipMemsetAsync(sums, 0, (size_t)NGRAPHS * NO * 4, stream);
    dim3 pg(NGRAPHS, 8);
    k_pool2<<<pg, 256, 0, stream>>>(h, batch, sums);
    k_final<<<NGRAPHS, 512, 0, stream>>>(sums, batch, Wlin, blin, out);
}

// Round 7
// 4081.754 us; speedup vs baseline: 2.5360x; 1.3787x over previous
//
#include <hip/hip_runtime.h>
#include <hip/hip_fp16.h>

#define NNODES 20000
#define NEDGES 640000
#define NGRAPHS 16
#define NO     256
#define NNF    58
#define KPAD   64
#define EMBD   512
#define NL     28

typedef __attribute__((ext_vector_type(8))) short bf16x8;
typedef __attribute__((ext_vector_type(4))) float f32x4;

__device__ __forceinline__ unsigned short f2bf(float f) {
    unsigned u = __float_as_uint(f);
    return (unsigned short)((u + 0x7fff + ((u >> 16) & 1)) >> 16);
}

// ---------------- CSR build (once per launch) ----------------
__global__ __launch_bounds__(256) void k_hist(const int* __restrict__ dst, int* __restrict__ counts) {
    int e = blockIdx.x * 256 + threadIdx.x;
    if (e < NEDGES) atomicAdd(&counts[dst[e]], 1);
}

__global__ __launch_bounds__(256) void k_scan(const int* __restrict__ counts, int* __restrict__ offs) {
    __shared__ int part[256];
    int t = threadIdx.x;
    const int CH = (NNODES + 255) / 256;  // 79
    int base = t * CH;
    int s = 0;
    for (int i = 0; i < CH; ++i) { int idx = base + i; if (idx < NNODES) s += counts[idx]; }
    part[t] = s;
    __syncthreads();
    if (t == 0) { int acc = 0; for (int i = 0; i < 256; ++i) { int v = part[i]; part[i] = acc; acc += v; } }
    __syncthreads();
    int acc = part[t];
    for (int i = 0; i < CH; ++i) { int idx = base + i; if (idx < NNODES) { offs[idx] = acc; acc += counts[idx]; } }
    if (t == 255) offs[NNODES] = acc;
}

__global__ __launch_bounds__(256) void k_copy(const int* __restrict__ a, int* __restrict__ b, int n) {
    int i = blockIdx.x * 256 + threadIdx.x;
    if (i < n) b[i] = a[i];
}

__global__ __launch_bounds__(256) void k_fill(const int* __restrict__ src, const int* __restrict__ dst,
                                              const float* __restrict__ ef, int* __restrict__ cursor,
                                              int* __restrict__ srcp, float* __restrict__ efp) {
    int e = blockIdx.x * 256 + threadIdx.x;
    if (e < NEDGES) {
        int d = dst[e];
        int pos = atomicAdd(&cursor[d], 1);
        srcp[pos] = src[e];
        efp[pos]  = ef[e];
    }
}

// ---------------- layer-0 input pad: [20000][58] -> [20000][64] ----------------
__global__ __launch_bounds__(256) void k_padx(const float* __restrict__ x, float* __restrict__ xpad) {
    int i = blockIdx.x * 256 + threadIdx.x;
    if (i < NNODES * KPAD) {
        int r = i >> 6, c = i & 63;
        xpad[i] = (c < NNF) ? x[r * NNF + c] : 0.f;
    }
}

// ---------------- weight precompute (bf16 hi/lo split) ----------------
// W rows: 0..255 = Wn; 256..511 = SCL*(Wm*diag(We))@Wn; 512..767 = SCL*(Wm*diag(be))@Wn
// Stored as Whi/Wlo: [NL][768][256] bf16 each. bcat fp32 [NL][768].
#define SCL 2.8853900817779268f

__global__ __launch_bounds__(256) void k_prepA(
    const float* __restrict__ Wn0, const float* __restrict__ bn0,
    const float* __restrict__ Wn,  const float* __restrict__ bn,
    unsigned short* __restrict__ Whi, unsigned short* __restrict__ Wlo,
    float* __restrict__ bcat) {
    int gid = blockIdx.x * 256 + threadIdx.x;
    if (gid >= NL * NO * NO) return;
    int l = gid / (NO * NO);
    int rem = gid % (NO * NO);
    int r = rem / NO, k = rem % NO;
    float w;
    if (l == 0) w = (k < NNF) ? Wn0[r * NNF + k] : 0.f;
    else        w = Wn[(size_t)(l - 1) * NO * NO + r * NO + k];
    unsigned short hi = f2bf(w);
    float hf = __uint_as_float(((unsigned)hi) << 16);
    unsigned short lo = f2bf(w - hf);
    size_t idx = ((size_t)l * 768 + r) * NO + k;
    Whi[idx] = hi; Wlo[idx] = lo;
    if (k == 0) bcat[l * 768 + r] = (l == 0) ? bn0[r] : bn[(l - 1) * NO + r];
}

__global__ __launch_bounds__(256) void k_prepB(
    const float* __restrict__ Wn0, const float* __restrict__ bn0,
    const float* __restrict__ We0, const float* __restrict__ be0,
    const float* __restrict__ Wm0, const float* __restrict__ bm0,
    const float* __restrict__ Wn,  const float* __restrict__ bn,
    const float* __restrict__ We,  const float* __restrict__ be,
    const float* __restrict__ Wm,  const float* __restrict__ bm,
    unsigned short* __restrict__ Whi, unsigned short* __restrict__ Wlo,
    float* __restrict__ bcat) {
    int l = blockIdx.x >> 4;            // 28 layers
    int rr0 = (blockIdx.x & 15) * 32;   // 512 rows / 32
    int k = threadIdx.x;                // 0..255
    const float *wn, *bnv, *wev, *bev, *wm, *bmv;
    int K;
    if (l == 0) { wn = Wn0; bnv = bn0; wev = We0; bev = be0; wm = Wm0; bmv = bm0; K = NNF; }
    else {
        int j = l - 1;
        wn = Wn + (size_t)j * NO * NO; bnv = bn + j * NO;
        wev = We + j * NO;             bev = be + j * NO;
        wm = Wm + (size_t)j * NO * NO; bmv = bm + j * NO;
        K = NO;
    }
    __shared__ float coeff[32][NO + 1];
    for (int q = 0; q < 32; ++q) {
        int rr = rr0 + q;
        int i = rr & 255;
        const float* scale = (rr < 256) ? wev : bev;
        coeff[q][k] = wm[(size_t)i * NO + k] * scale[k];
    }
    __syncthreads();
    float acc[32] = {};
    if (k < K) {
        for (int j = 0; j < NO; ++j) {
            float wv = wn[(size_t)j * K + k];
            #pragma unroll
            for (int q = 0; q < 32; ++q) acc[q] += coeff[q][j] * wv;
        }
    }
    for (int q = 0; q < 32; ++q) {
        float w = (k < K) ? acc[q] * SCL : 0.f;
        unsigned short hi = f2bf(w);
        float hf = __uint_as_float(((unsigned)hi) << 16);
        unsigned short lo = f2bf(w - hf);
        size_t idx = ((size_t)l * 768 + 256 + rr0 + q) * NO + k;
        Whi[idx] = hi; Wlo[idx] = lo;
    }
    if (k < 32) {
        int rr = rr0 + k;
        int i = rr & 255;
        float b = 0.f;
        for (int j = 0; j < NO; ++j) b += coeff[k][j] * bnv[j];
        if (rr >= 256) b += bmv[i];
        bcat[l * 768 + 256 + rr] = b * SCL;
    }
}

// ---------------- MFMA layer GEMM: [hn | u | v] = A[M x K] @ W[768 x K].T + bias ----------------
// split-bf16: A = Ahi + Alo (on-the-fly), W = Whi + Wlo (precomputed).
// acc += Whi*Ahi + Whi*Alo + Wlo*Ahi  (3 mfma passes, fp32 AGPR accum).
// mfma_f32_16x16x32_bf16: arg0 (A-role) rows via l&15; arg1 (B-role) cols via l&15;
// D: row = 4*(l>>4)+r, col = l&15. W as arg0 -> each lane's D = 4 consecutive out-cols of 1 node row.
// 128x128 block tile, 4 waves (2x2 of 64x64). LDS rows padded to 40 shorts (80B, 2-way bank = free).
#define LDP 40
__global__ __launch_bounds__(256) void k_gemm(const float* __restrict__ A,
                                              const unsigned short* __restrict__ Whi,
                                              const unsigned short* __restrict__ Wlo,
                                              const float* __restrict__ bias,
                                              float* __restrict__ HN, __half* __restrict__ UV,
                                              int M, int K) {
    __shared__ short sAhi[128 * LDP];
    __shared__ short sAlo[128 * LDP];
    __shared__ short sBhi[128 * LDP];
    __shared__ short sBlo[128 * LDP];
    int bn0 = blockIdx.x * 128;
    int bm0 = blockIdx.y * 128;
    int t = threadIdx.x;
    int wid = t >> 6, lane = t & 63;
    int wr = wid >> 1, wc = wid & 1;
    int lr = lane & 15, lg = lane >> 4;
    int kofs = lg * 8;
    f32x4 acc[4][4] = {};

    int srow = t >> 1, skh = (t & 1) * 16;   // staging assignment: half a k-row each

    for (int k0 = 0; k0 < K; k0 += 32) {
        // ---- stage A (fp32 -> bf16 hi/lo) ----
        {
            int gr = bm0 + srow;
            float f[16];
            if (gr < M) {
                #pragma unroll
                for (int q = 0; q < 4; ++q)
                    *(float4*)(f + 4 * q) = *(const float4*)(A + (size_t)gr * K + k0 + skh + 4 * q);
            } else {
                #pragma unroll
                for (int q = 0; q < 16; ++q) f[q] = 0.f;
            }
            int ph[8], pl[8];
            #pragma unroll
            for (int q = 0; q < 8; ++q) {
                unsigned short h0 = f2bf(f[2 * q]);
                unsigned short h1 = f2bf(f[2 * q + 1]);
                float hf0 = __uint_as_float(((unsigned)h0) << 16);
                float hf1 = __uint_as_float(((unsigned)h1) << 16);
                unsigned short l0 = f2bf(f[2 * q] - hf0);
                unsigned short l1 = f2bf(f[2 * q + 1] - hf1);
                ph[q] = (int)h0 | ((int)h1 << 16);
                pl[q] = (int)l0 | ((int)l1 << 16);
            }
            *(int4*)(void*)(sAhi + srow * LDP + skh)     = *(int4*)(void*)(ph);
            *(int4*)(void*)(sAhi + srow * LDP + skh + 8) = *(int4*)(void*)(ph + 4);
            *(int4*)(void*)(sAlo + srow * LDP + skh)     = *(int4*)(void*)(pl);
            *(int4*)(void*)(sAlo + srow * LDP + skh + 8) = *(int4*)(void*)(pl + 4);
        }
        // ---- stage W hi/lo (straight copy) ----
        {
            const unsigned short* gh = Whi + (size_t)(bn0 + srow) * NO + k0 + skh;
            const unsigned short* gl = Wlo + (size_t)(bn0 + srow) * NO + k0 + skh;
            *(int4*)(void*)(sBhi + srow * LDP + skh)     = *(const int4*)(void*)(gh);
            *(int4*)(void*)(sBhi + srow * LDP + skh + 8) = *(const int4*)(void*)(gh + 8);
            *(int4*)(void*)(sBlo + srow * LDP + skh)     = *(const int4*)(void*)(gl);
            *(int4*)(void*)(sBlo + srow * LDP + skh + 8) = *(const int4*)(void*)(gl + 8);
        }
        __syncthreads();
        // ---- fragments + MFMA ----
        bf16x8 ah[4], al[4], wh[4], wl[4];
        #pragma unroll
        for (int f = 0; f < 4; ++f) {
            ah[f] = *(bf16x8*)(void*)(sAhi + (wr * 64 + f * 16 + lr) * LDP + kofs);
            al[f] = *(bf16x8*)(void*)(sAlo + (wr * 64 + f * 16 + lr) * LDP + kofs);
            wh[f] = *(bf16x8*)(void*)(sBhi + (wc * 64 + f * 16 + lr) * LDP + kofs);
            wl[f] = *(bf16x8*)(void*)(sBlo + (wc * 64 + f * 16 + lr) * LDP + kofs);
        }
        #pragma unroll
        for (int fc = 0; fc < 4; ++fc)
            #pragma unroll
            for (int fr = 0; fr < 4; ++fr) {
                acc[fc][fr] = __builtin_amdgcn_mfma_f32_16x16x32_bf16(wh[fc], ah[fr], acc[fc][fr], 0, 0, 0);
                acc[fc][fr] = __builtin_amdgcn_mfma_f32_16x16x32_bf16(wh[fc], al[fr], acc[fc][fr], 0, 0, 0);
                acc[fc][fr] = __builtin_amdgcn_mfma_f32_16x16x32_bf16(wl[fc], ah[fr], acc[fc][fr], 0, 0, 0);
            }
        __syncthreads();
    }
    // ---- epilogue ----
    #pragma unroll
    for (int fc = 0; fc < 4; ++fc) {
        int n0 = bn0 + wc * 64 + fc * 16 + lg * 4;   // 4 consecutive out-cols
        float4 bi = *(const float4*)(bias + n0);
        #pragma unroll
        for (int fr = 0; fr < 4; ++fr) {
            int gr = bm0 + wr * 64 + fr * 16 + lr;
            if (gr >= M) continue;
            f32x4 v = acc[fc][fr];
            float o0 = v[0] + bi.x, o1 = v[1] + bi.y, o2 = v[2] + bi.z, o3 = v[3] + bi.w;
            if (n0 < 256) {
                float4 o = {o0, o1, o2, o3};
                *(float4*)(HN + (size_t)gr * NO + n0) = o;
            } else {
                int i0 = (n0 < 512) ? n0 - 256 : n0 - 512;   // multiple of 4
                int base = 2 * i0 + ((n0 < 512) ? 0 : 4);
                union { __half2 h2[2]; uint2 u; } pk;
                pk.h2[0] = __floats2half2_rn(o0, o1);
                pk.h2[1] = __floats2half2_rn(o2, o3);
                *(uint2*)(UV + (size_t)gr * 512 + base) = pk.u;
            }
        }
    }
}

// ---------------- edge aggregation: wave-per-node, fp16 u/v gather ----------------
__global__ __launch_bounds__(256) void k_edge(const float* __restrict__ HN, const __half* __restrict__ UV,
                                              const int* __restrict__ offs,
                                              const int* __restrict__ srcp, const float* __restrict__ efp,
                                              float* __restrict__ hout) {
    int wv = threadIdx.x >> 6;
    int lane = threadIdx.x & 63;
    int n = blockIdx.x * 4 + wv;
    int e0 = offs[n], e1 = offs[n + 1];
    float a0 = 0.f, a1 = 0.f, a2 = 0.f, a3 = 0.f;
    for (int eb = e0; eb < e1; eb += 64) {
        int cnt = e1 - eb; if (cnt > 64) cnt = 64;
        int sv = 0; float fv = 0.f;
        if (lane < cnt) { sv = srcp[eb + lane]; fv = efp[eb + lane]; }
        #pragma unroll 4
        for (int i = 0; i < cnt; ++i) {
            int ss = __shfl(sv, i);
            float ff = __shfl(fv, i);
            float4 raw = *(const float4*)(UV + (size_t)ss * 512 + lane * 8);
            const __half2* hp = (const __half2*)&raw;
            float2 u01 = __half22float2(hp[0]);
            float2 u23 = __half22float2(hp[1]);
            float2 v01 = __half22float2(hp[2]);
            float2 v23 = __half22float2(hp[3]);
            float g0 = exp2f(fmaf(ff, u01.x, v01.x));
            float g1 = exp2f(fmaf(ff, u01.y, v01.y));
            float g2 = exp2f(fmaf(ff, u23.x, v23.x));
            float g3 = exp2f(fmaf(ff, u23.y, v23.y));
            a0 += 1.0f - 2.0f * __builtin_amdgcn_rcpf(g0 + 1.0f);
            a1 += 1.0f - 2.0f * __builtin_amdgcn_rcpf(g1 + 1.0f);
            a2 += 1.0f - 2.0f * __builtin_amdgcn_rcpf(g2 + 1.0f);
            a3 += 1.0f - 2.0f * __builtin_amdgcn_rcpf(g3 + 1.0f);
        }
    }
    float4 hn4 = *(const float4*)(HN + (size_t)n * NO + lane * 4);
    float4 o = {hn4.x + a0, hn4.y + a1, hn4.z + a2, hn4.w + a3};
    *(float4*)(hout + (size_t)n * NO + lane * 4) = o;
}

// ---------------- pooling via sorted-batch ranges ----------------
__device__ __forceinline__ int lower_bound_g(const int* __restrict__ batch, int target) {
    int lo = 0, hi = NNODES;
    while (lo < hi) { int mid = (lo + hi) >> 1; if (batch[mid] < target) lo = mid + 1; else hi = mid; }
    return lo;
}

__global__ __launch_bounds__(256) void k_pool2(const float* __restrict__ h, const int* __restrict__ batch,
                                               float* __restrict__ sums) {
    int g = blockIdx.x, chunk = blockIdx.y;
    __shared__ int sh[2];
    if (threadIdx.x < 2) sh[threadIdx.x] = lower_bound_g(batch, g + (int)threadIdx.x);
    __syncthreads();
    int lo = sh[0], hi = sh[1];
    float acc = 0.f;
    for (int r = lo + chunk; r < hi; r += 8)
        acc += h[(size_t)r * NO + threadIdx.x];
    atomicAdd(&sums[g * NO + threadIdx.x], acc);
}

__global__ __launch_bounds__(512) void k_final(const float* __restrict__ sums, const int* __restrict__ batch,
                                               const float* __restrict__ Wlin, const float* __restrict__ blin,
                                               float* __restrict__ out) {
    int g = blockIdx.x, t = threadIdx.x;
    __shared__ int sh[2];
    __shared__ float m[NO];
    if (t < 2) sh[t] = lower_bound_g(batch, g + t);
    __syncthreads();
    float inv = 1.f / (float)(sh[1] - sh[0]);
    if (t < NO) m[t] = sums[g * NO + t] * inv;
    __syncthreads();
    float acc = blin[t];
    for (int k = 0; k < NO; ++k) acc += m[k] * Wlin[(size_t)t * NO + k];
    out[(size_t)g * EMBD + t] = acc;
}

extern "C" void kernel_launch(void* const* d_in, const int* in_sizes, int n_in,
                              void* d_out, int out_size, void* d_ws, size_t ws_size,
                              hipStream_t stream) {
    const float* x     = (const float*)d_in[0];
    const int*   ei    = (const int*)d_in[1];
    const float* ef    = (const float*)d_in[2];
    const int*   batch = (const int*)d_in[3];
    const float* Wn0 = (const float*)d_in[4];
    const float* bn0 = (const float*)d_in[5];
    const float* We0 = (const float*)d_in[6];
    const float* be0 = (const float*)d_in[7];
    const float* Wm0 = (const float*)d_in[8];
    const float* bm0 = (const float*)d_in[9];
    const float* Wn  = (const float*)d_in[10];
    const float* bn  = (const float*)d_in[11];
    const float* We  = (const float*)d_in[12];
    const float* be  = (const float*)d_in[13];
    const float* Wm  = (const float*)d_in[14];
    const float* bm  = (const float*)d_in[15];
    const float* Wlin = (const float*)d_in[16];
    const float* blin = (const float*)d_in[17];
    float* out = (float*)d_out;

    // workspace carve (256B aligned slices)
    char* p = (char*)d_ws;
    auto carve = [&](size_t bytes) { char* q = p; p += (bytes + 255) & ~(size_t)255; return q; };
    float*  h    = (float*)carve((size_t)NNODES * NO * 4);            // 20.48 MB
    float*  HN   = (float*)carve((size_t)NNODES * NO * 4);            // 20.48 MB
    __half* UV   = (__half*)carve((size_t)NNODES * 512 * 2);          // 20.48 MB
    unsigned short* Whi = (unsigned short*)carve((size_t)NL * 768 * NO * 2);  // 11.0 MB
    unsigned short* Wlo = (unsigned short*)carve((size_t)NL * 768 * NO * 2);  // 11.0 MB
    float*  bcat = (float*)carve((size_t)NL * 768 * 4);
    float*  xpad = (float*)carve((size_t)NNODES * KPAD * 4);          // 5.12 MB
    int*    offs = (int*)carve((size_t)(NNODES + 1) * 4);
    int*    cur  = (int*)carve((size_t)NNODES * 4);
    int*    srcp = (int*)carve((size_t)NEDGES * 4);
    float*  efp  = (float*)carve((size_t)NEDGES * 4);
    float*  sums = (float*)carve((size_t)NGRAPHS * NO * 4);

    const int* src = ei;
    const int* dst = ei + NEDGES;

    // CSR build
    hipMemsetAsync(cur, 0, (size_t)NNODES * 4, stream);
    k_hist<<<NEDGES / 256, 256, 0, stream>>>(dst, cur);
    k_scan<<<1, 256, 0, stream>>>(cur, offs);
    k_copy<<<(NNODES + 255) / 256, 256, 0, stream>>>(offs, cur, NNODES);
    k_fill<<<NEDGES / 256, 256, 0, stream>>>(src, dst, ef, cur, srcp, efp);

    // layer-0 padded input + composed per-layer weights (bf16 hi/lo)
    k_padx<<<(NNODES * KPAD + 255) / 256, 256, 0, stream>>>(x, xpad);
    k_prepA<<<(NL * NO * NO + 255) / 256, 256, 0, stream>>>(Wn0, bn0, Wn, bn, Whi, Wlo, bcat);
    k_prepB<<<NL * 16, 256, 0, stream>>>(Wn0, bn0, We0, be0, Wm0, bm0,
                                         Wn, bn, We, be, Wm, bm, Whi, Wlo, bcat);

    // 28 layers
    for (int l = 0; l < NL; ++l) {
        const float* Ain = (l == 0) ? xpad : h;
        int K = (l == 0) ? KPAD : NO;
        dim3 grid(768 / 128, (NNODES + 127) / 128);
        k_gemm<<<grid, 256, 0, stream>>>(Ain, Whi + (size_t)l * 768 * NO, Wlo + (size_t)l * 768 * NO,
                                         bcat + (size_t)l * 768, HN, UV, NNODES, K);
        k_edge<<<NNODES / 4, 256, 0, stream>>>(HN, UV, offs, srcp, efp, h);
    }

    // mean-pool via sorted ranges, then tiny final GEMM
    hipMemsetAsync(sums, 0, (size_t)NGRAPHS * NO * 4, stream);
    dim3 pg(NGRAPHS, 8);
    k_pool2<<<pg, 256, 0, stream>>>(h, batch, sums);
    k_final<<<NGRAPHS, 512, 0, stream>>>(sums, batch, Wlin, blin, out);
}